// Round 6
// baseline (444.545 us; speedup 1.0000x reference)
//
#include <hip/hip_runtime.h>
#include <cstdint>
#include <cstddef>

typedef __bf16 bf16;
typedef __bf16 bf16x4 __attribute__((ext_vector_type(4)));
typedef __bf16 bf16x8 __attribute__((ext_vector_type(8)));
typedef float  f32x4  __attribute__((ext_vector_type(4)));

#define BATCH 4
#define SEQ   2048
#define DIM   1024

// RNE float -> bf16
__device__ __forceinline__ bf16 to_bf16(float f) {
    unsigned u = __builtin_bit_cast(unsigned, f);
    u += 0x7fffu + ((u >> 16) & 1u);
    unsigned short h = (unsigned short)(u >> 16);
    return __builtin_bit_cast(bf16, h);
}

// async global->LDS, 16B per lane. LDS base must be wave-uniform; HW adds lane*16.
__device__ __forceinline__ void load16_lds(const bf16* g, bf16* l) {
    __builtin_amdgcn_global_load_lds(
        (__attribute__((address_space(1))) void*)(g),
        (__attribute__((address_space(3))) void*)(l),
        16, 0, 0);
}

// ---------------------------------------------------------------------------
// BK=64 core, XOR-swizzled LDS chunk layout (physical chunk = logical ^ (row&7)
// -> 2-way-max bank aliasing, measured 0 conflicts). BM=128, BN=128.
// 4 waves as 2x2, wave-tile 64x64, acc[4][4].
// ---------------------------------------------------------------------------
__device__ __forceinline__ void gemm_core64(
    const bf16* __restrict__ Abase, const bf16* __restrict__ Bbase,
    int K, int lda, int ldb, bf16* As, bf16* Bs, f32x4 acc[4][4])
{
    const int tid  = threadIdx.x;
    const int lane = tid & 63;
    const int wave = tid >> 6;
    const int wm   = (wave >> 1) * 64;
    const int wn   = (wave & 1) * 64;
    const int r16  = lane & 15;
    const int g    = lane >> 4;
    const int srow0 = wave * 8 + (lane >> 3);
    const int scoff = (((lane & 7) ^ ((lane >> 3) & 7)) * 8);
    const int ldsW  = wave * 512;

    for (int k0 = 0; k0 < K; k0 += 64) {
        __syncthreads();
#pragma unroll
        for (int j = 0; j < 4; ++j) {
            load16_lds(Abase + (size_t)(j * 32 + srow0) * lda + k0 + scoff,
                       As + j * 2048 + ldsW);
            load16_lds(Bbase + (size_t)(j * 32 + srow0) * ldb + k0 + scoff,
                       Bs + j * 2048 + ldsW);
        }
        __syncthreads();

#pragma unroll
        for (int h = 0; h < 2; ++h) {
            bf16x8 af[4], bfr[4];
            const int p = (h * 4 + g) ^ (r16 & 7);
#pragma unroll
            for (int i = 0; i < 4; ++i) {
                af[i]  = *(const bf16x8*)(As + (wm + i * 16 + r16) * 64 + p * 8);
                bfr[i] = *(const bf16x8*)(Bs + (wn + i * 16 + r16) * 64 + p * 8);
            }
#pragma unroll
            for (int mi = 0; mi < 4; ++mi)
#pragma unroll
                for (int ni = 0; ni < 4; ++ni)
                    acc[mi][ni] = __builtin_amdgcn_mfma_f32_16x16x32_bf16(
                        af[mi], bfr[ni], acc[mi][ni], 0, 0, 0);
        }
    }
}

// ---------------------------------------------------------------------------
// Merged projection GEMM: blocks [0,1024) -> QK = X @ WqkT^T ([8192,2048]);
// blocks [1024,1536) -> Vt[b] = WvT @ X[b]^T ([1024,2048]/batch).
// 5 blocks/CU: LDS 5x32KB = 160KB exact, VGPR <= 102.
// ---------------------------------------------------------------------------
__global__ __launch_bounds__(256, 5) void proj_gemm(
    const bf16* __restrict__ xb, const bf16* __restrict__ Wt,
    bf16* __restrict__ QK, bf16* __restrict__ Vt)
{
    __shared__ bf16 As[8192];
    __shared__ bf16 Bs[8192];
    f32x4 acc[4][4] = {};

    const int r = blockIdx.x;
    const bf16 *Ab, *Bb;
    bf16* Cb;
    int bx, byl;
    if (r < 1024) {                       // QK part
        const int c = r & 7, j = r >> 3;
        bx  = j & 15;
        byl = c + 8 * (j >> 4);
        Ab = xb + (size_t)byl * 128 * DIM;
        Bb = Wt + (size_t)bx * 128 * DIM;
        Cb = QK + (size_t)byl * 128 * 2048;
    } else {                              // Vt part
        const int u = r - 1024;
        const int c = u & 7, j = u >> 3;
        bx = j & 15;
        const int p = c + 8 * (j >> 4);
        byl = p & 7;
        const int bz = p >> 3;
        Ab = Wt + (size_t)2 * DIM * DIM + (size_t)byl * 128 * DIM;
        Bb = xb + (size_t)bz * SEQ * DIM + (size_t)bx * 128 * DIM;
        Cb = Vt + (size_t)bz * DIM * SEQ + (size_t)byl * 128 * 2048;
    }
    gemm_core64(Ab, Bb, DIM, DIM, DIM, As, Bs, acc);

    const int lane = threadIdx.x & 63;
    const int wave = threadIdx.x >> 6;
    const int wm = (wave >> 1) * 64, wn = (wave & 1) * 64;
    const int rowO = wm + ((lane >> 4) * 4);
    const int colO = bx * 128 + wn + (lane & 15);
#pragma unroll
    for (int mi = 0; mi < 4; ++mi)
#pragma unroll
        for (int ni = 0; ni < 4; ++ni)
#pragma unroll
            for (int rr = 0; rr < 4; ++rr)
                Cb[(size_t)(rowO + mi * 16 + rr) * 2048 + colO + ni * 16] =
                    to_bf16(acc[mi][ni][rr]);
}

// ---------------------------------------------------------------------------
// scores GEMM: P' = exp((Q @ K^T)/32) (bf16), fp32 row sums via atomics.
// grid = (16, 16, 4), 5 blocks/CU.
// ---------------------------------------------------------------------------
__global__ __launch_bounds__(256, 5) void gemm_scores(
    const bf16* __restrict__ A, const bf16* __restrict__ Bm, bf16* __restrict__ C,
    float* __restrict__ lsum)
{
    __shared__ bf16 As[8192];
    __shared__ bf16 Bs[8192];
    f32x4 acc[4][4] = {};

    const int d = blockIdx.x + 16 * (blockIdx.y + 16 * blockIdx.z);
    const int c = d & 7, j = d >> 3;
    const int bx = j & 15;
    const int p = c + 8 * (j >> 4);
    const int by = p & 15, bz = p >> 4;

    const int lda = 2 * DIM;
    const bf16* Ab = A  + (size_t)bz * SEQ * lda + (size_t)by * 128 * lda;
    const bf16* Bb = Bm + (size_t)bz * SEQ * lda + (size_t)bx * 128 * lda;
    bf16* Cb = C + (size_t)bz * SEQ * SEQ;
    gemm_core64(Ab, Bb, DIM, lda, lda, As, Bs, acc);

    const int lane = threadIdx.x & 63;
    const int wave = threadIdx.x >> 6;
    const int wm = (wave >> 1) * 64, wn = (wave & 1) * 64;
    const int rowBase = by * 128 + wm + ((lane >> 4) * 4);
    const int colBase = bx * 128 + wn + (lane & 15);

#pragma unroll
    for (int mi = 0; mi < 4; ++mi)
#pragma unroll
        for (int ni = 0; ni < 4; ++ni)
#pragma unroll
            for (int rr = 0; rr < 4; ++rr) {
                const float e = __expf(acc[mi][ni][rr] * 0.03125f);
                acc[mi][ni][rr] = e;
                Cb[(size_t)(rowBase + mi * 16 + rr) * SEQ + colBase + ni * 16] =
                    to_bf16(e);
            }

    float* ls = lsum + (size_t)bz * SEQ;
#pragma unroll
    for (int mi = 0; mi < 4; ++mi)
#pragma unroll
        for (int rr = 0; rr < 4; ++rr) {
            float s = acc[mi][0][rr] + acc[mi][1][rr] + acc[mi][2][rr] + acc[mi][3][rr];
            s += __shfl_xor(s, 1);
            s += __shfl_xor(s, 2);
            s += __shfl_xor(s, 4);
            s += __shfl_xor(s, 8);
            if ((lane & 15) == 0)
                atomicAdd(ls + rowBase + mi * 16 + rr, s);
        }
}

// ---------------------------------------------------------------------------
// PV GEMM, K-split=2: each block computes a K=1024 partial of
// (P' @ Vt^T)/l at BM=128 and atomicAdds fp32 into out (pre-zeroed).
// grid = (8, 16, 8): z = bz*2 + half -> 1024 blocks = 4/CU.
// ---------------------------------------------------------------------------
__global__ __launch_bounds__(256, 4) void gemm_pv(
    const bf16* __restrict__ A, const bf16* __restrict__ Bm, float* __restrict__ C,
    const float* __restrict__ lsum)
{
    __shared__ bf16 As[8192];
    __shared__ bf16 Bs[8192];
    f32x4 acc[4][4] = {};

    const int d = blockIdx.x + 8 * (blockIdx.y + 16 * blockIdx.z);
    const int c = d & 7, j = d >> 3;
    const int bx = j & 7;
    const int p = c + 8 * (j >> 3);
    const int by = p & 15;
    const int z  = p >> 4;              // 0..7
    const int bz = z >> 1, half = z & 1;

    const bf16* Ab = A  + (size_t)bz * SEQ * SEQ + (size_t)by * 128 * SEQ + half * 1024;
    const bf16* Bb = Bm + (size_t)bz * DIM * SEQ + (size_t)bx * 128 * SEQ + half * 1024;
    float* Cb = C + (size_t)bz * SEQ * DIM;
    gemm_core64(Ab, Bb, 1024, SEQ, SEQ, As, Bs, acc);

    const int lane = threadIdx.x & 63;
    const int wave = threadIdx.x >> 6;
    const int wm = (wave >> 1) * 64, wn = (wave & 1) * 64;
    const int rowBase = by * 128 + wm + ((lane >> 4) * 4);
    const int colBase = bx * 128 + wn + (lane & 15);
    const float* ls = lsum + (size_t)bz * SEQ;
#pragma unroll
    for (int mi = 0; mi < 4; ++mi)
#pragma unroll
        for (int rr = 0; rr < 4; ++rr) {
            const float inv = __builtin_amdgcn_rcpf(ls[rowBase + mi * 16 + rr]);
#pragma unroll
            for (int ni = 0; ni < 4; ++ni)
                atomicAdd(&Cb[(size_t)(rowBase + mi * 16 + rr) * DIM + colBase + ni * 16],
                          acc[mi][ni][rr] * inv);
        }
}

// ---------------------------------------------------------------------------
// Fused prep: blocks [0,8192) cast x fp32->bf16; blocks [8192,11264) transpose
// + cast weights; block 11264 zeroes lsum. All branches block-uniform.
// ---------------------------------------------------------------------------
__global__ __launch_bounds__(256) void prep(
    const float* __restrict__ x,  const float* __restrict__ wq,
    const float* __restrict__ wk, const float* __restrict__ wv,
    bf16* __restrict__ xb, bf16* __restrict__ Wt, float* __restrict__ lsum)
{
    __shared__ float tile[32][33];
    const int b = blockIdx.x;
    const int tid = threadIdx.x;
    if (b < 8192) {
        const size_t i = ((size_t)b * 256 + tid) * 4;
        const float4 v = *(const float4*)(x + i);
        bf16x4 o = { to_bf16(v.x), to_bf16(v.y), to_bf16(v.z), to_bf16(v.w) };
        *(bf16x4*)(xb + i) = o;
    } else if (b < 8192 + 3072) {
        const int t   = b - 8192;
        const int sel = t >> 10;
        const int n0  = (t & 31) * 32;
        const int k0  = ((t >> 5) & 31) * 32;
        const float* w = (sel == 0) ? wq : (sel == 1) ? wk : wv;
        const int tx = tid & 31, ty = tid >> 5;
#pragma unroll
        for (int j = 0; j < 32; j += 8)
            tile[ty + j][tx] = w[(size_t)(k0 + ty + j) * 1024 + n0 + tx];
        __syncthreads();
        bf16* dst = Wt + (size_t)sel * 1024 * 1024;
#pragma unroll
        for (int j = 0; j < 32; j += 8)
            dst[(size_t)(n0 + ty + j) * 1024 + k0 + tx] = to_bf16(tile[tx][ty + j]);
    } else {
#pragma unroll
        for (int i = 0; i < 32; ++i)
            lsum[i * 256 + tid] = 0.0f;
    }
}

// ---------------------------------------------------------------------------
extern "C" void kernel_launch(void* const* d_in, const int* in_sizes, int n_in,
                              void* d_out, int out_size, void* d_ws, size_t ws_size,
                              hipStream_t stream)
{
    const float* x  = (const float*)d_in[0];
    const float* wq = (const float*)d_in[1];
    const float* wk = (const float*)d_in[2];
    const float* wv = (const float*)d_in[3];
    float* out = (float*)d_out;
    char* ws = (char*)d_ws;

    // workspace layout (bytes)
    bf16*  xb   = (bf16*)(ws);                   // 16 MB [8192,1024]
    bf16*  Wt   = (bf16*)(ws + (16u << 20));     //  6 MB [3072,1024] (WqT|WkT|WvT)
    bf16*  QK   = (bf16*)(ws + (22u << 20));     // 32 MB [8192,2048]
    bf16*  Vt   = (bf16*)(ws + (54u << 20));     // 16 MB [4][1024][2048]
    bf16*  P    = (bf16*)(ws + (70u << 20));     // 32 MB [4,2048,2048]
    float* lsum = (float*)(ws + (102u << 20));   // 32 KB [8192]

    // zero out for K-split atomic accumulation (graph-capture safe)
    hipMemsetAsync(out, 0, (size_t)BATCH * SEQ * DIM * sizeof(float), stream);

    prep<<<dim3(8192 + 3072 + 1), dim3(256), 0, stream>>>(
        x, wq, wk, wv, xb, Wt, lsum);

    // QK + Vt in one dispatch
    proj_gemm<<<dim3(1536), dim3(256), 0, stream>>>(xb, Wt, QK, Vt);

    // P' = exp(Q @ K^T / 32), row sums -> lsum
    gemm_scores<<<dim3(16, 16, 4), dim3(256), 0, stream>>>(QK, QK + DIM, P, lsum);

    // out += (P'_half @ Vt^T) / l, K-split=2
    gemm_pv<<<dim3(8, 16, 8), dim3(256), 0, stream>>>(P, Vt, out, lsum);
}

// Round 7
// 279.500 us; speedup vs baseline: 1.5905x; 1.5905x over previous
//
#include <hip/hip_runtime.h>
#include <cstdint>
#include <cstddef>

typedef __bf16 bf16;
typedef __bf16 bf16x4 __attribute__((ext_vector_type(4)));
typedef __bf16 bf16x8 __attribute__((ext_vector_type(8)));
typedef float  f32x4  __attribute__((ext_vector_type(4)));

#define BATCH 4
#define SEQ   2048
#define DIM   1024

// RNE float -> bf16
__device__ __forceinline__ bf16 to_bf16(float f) {
    unsigned u = __builtin_bit_cast(unsigned, f);
    u += 0x7fffu + ((u >> 16) & 1u);
    unsigned short h = (unsigned short)(u >> 16);
    return __builtin_bit_cast(bf16, h);
}

// async global->LDS, 16B per lane. LDS base must be wave-uniform; HW adds lane*16.
__device__ __forceinline__ void load16_lds(const bf16* g, bf16* l) {
    __builtin_amdgcn_global_load_lds(
        (__attribute__((address_space(1))) void*)(g),
        (__attribute__((address_space(3))) void*)(l),
        16, 0, 0);
}

// ---------------------------------------------------------------------------
// BK=64 core, XOR-swizzled LDS chunk layout (physical chunk = logical ^ (row&7)
// -> 2-way-max bank aliasing, measured 0 conflicts). BM=128, BN=128.
// 4 waves as 2x2, wave-tile 64x64, acc[4][4] (= 64 VGPR accumulator footprint;
// launch_bounds waves/EU MUST stay <= 4 or the allocator spills — measured
// R6: (256,5) forced VGPR 48 -> 419 MB scratch writes, 2.8x slowdown).
// ---------------------------------------------------------------------------
__device__ __forceinline__ void gemm_core64(
    const bf16* __restrict__ Abase, const bf16* __restrict__ Bbase,
    int K, int lda, int ldb, bf16* As, bf16* Bs, f32x4 acc[4][4])
{
    const int tid  = threadIdx.x;
    const int lane = tid & 63;
    const int wave = tid >> 6;
    const int wm   = (wave >> 1) * 64;
    const int wn   = (wave & 1) * 64;
    const int r16  = lane & 15;
    const int g    = lane >> 4;
    const int srow0 = wave * 8 + (lane >> 3);
    const int scoff = (((lane & 7) ^ ((lane >> 3) & 7)) * 8);
    const int ldsW  = wave * 512;

    for (int k0 = 0; k0 < K; k0 += 64) {
        __syncthreads();
#pragma unroll
        for (int j = 0; j < 4; ++j) {
            load16_lds(Abase + (size_t)(j * 32 + srow0) * lda + k0 + scoff,
                       As + j * 2048 + ldsW);
            load16_lds(Bbase + (size_t)(j * 32 + srow0) * ldb + k0 + scoff,
                       Bs + j * 2048 + ldsW);
        }
        __syncthreads();

#pragma unroll
        for (int h = 0; h < 2; ++h) {
            bf16x8 af[4], bfr[4];
            const int p = (h * 4 + g) ^ (r16 & 7);
#pragma unroll
            for (int i = 0; i < 4; ++i) {
                af[i]  = *(const bf16x8*)(As + (wm + i * 16 + r16) * 64 + p * 8);
                bfr[i] = *(const bf16x8*)(Bs + (wn + i * 16 + r16) * 64 + p * 8);
            }
#pragma unroll
            for (int mi = 0; mi < 4; ++mi)
#pragma unroll
                for (int ni = 0; ni < 4; ++ni)
                    acc[mi][ni] = __builtin_amdgcn_mfma_f32_16x16x32_bf16(
                        af[mi], bfr[ni], acc[mi][ni], 0, 0, 0);
        }
    }
}

// ---------------------------------------------------------------------------
// Merged projection GEMM: blocks [0,1024) -> QK = X @ WqkT^T ([8192,2048]);
// blocks [1024,1536) -> Vt[b] = WvT @ X[b]^T ([1024,2048]/batch).
// ---------------------------------------------------------------------------
__global__ __launch_bounds__(256, 4) void proj_gemm(
    const bf16* __restrict__ xb, const bf16* __restrict__ Wt,
    bf16* __restrict__ QK, bf16* __restrict__ Vt)
{
    __shared__ bf16 As[8192];
    __shared__ bf16 Bs[8192];
    f32x4 acc[4][4] = {};

    const int r = blockIdx.x;
    const bf16 *Ab, *Bb;
    bf16* Cb;
    int bx, byl;
    if (r < 1024) {                       // QK part
        const int c = r & 7, j = r >> 3;
        bx  = j & 15;
        byl = c + 8 * (j >> 4);
        Ab = xb + (size_t)byl * 128 * DIM;
        Bb = Wt + (size_t)bx * 128 * DIM;
        Cb = QK + (size_t)byl * 128 * 2048;
    } else {                              // Vt part
        const int u = r - 1024;
        const int c = u & 7, j = u >> 3;
        bx = j & 15;
        const int p = c + 8 * (j >> 4);
        byl = p & 7;
        const int bz = p >> 3;
        Ab = Wt + (size_t)2 * DIM * DIM + (size_t)byl * 128 * DIM;
        Bb = xb + (size_t)bz * SEQ * DIM + (size_t)bx * 128 * DIM;
        Cb = Vt + (size_t)bz * DIM * SEQ + (size_t)byl * 128 * 2048;
    }
    gemm_core64(Ab, Bb, DIM, DIM, DIM, As, Bs, acc);

    const int lane = threadIdx.x & 63;
    const int wave = threadIdx.x >> 6;
    const int wm = (wave >> 1) * 64, wn = (wave & 1) * 64;
    const int rowO = wm + ((lane >> 4) * 4);
    const int colO = bx * 128 + wn + (lane & 15);
#pragma unroll
    for (int mi = 0; mi < 4; ++mi)
#pragma unroll
        for (int ni = 0; ni < 4; ++ni)
#pragma unroll
            for (int rr = 0; rr < 4; ++rr)
                Cb[(size_t)(rowO + mi * 16 + rr) * 2048 + colO + ni * 16] =
                    to_bf16(acc[mi][ni][rr]);
}

// ---------------------------------------------------------------------------
// scores GEMM: P' = exp((Q @ K^T)/32) (bf16), fp32 row sums via atomics.
// grid = (16, 16, 4)
// ---------------------------------------------------------------------------
__global__ __launch_bounds__(256, 4) void gemm_scores(
    const bf16* __restrict__ A, const bf16* __restrict__ Bm, bf16* __restrict__ C,
    float* __restrict__ lsum)
{
    __shared__ bf16 As[8192];
    __shared__ bf16 Bs[8192];
    f32x4 acc[4][4] = {};

    const int d = blockIdx.x + 16 * (blockIdx.y + 16 * blockIdx.z);
    const int c = d & 7, j = d >> 3;
    const int bx = j & 15;
    const int p = c + 8 * (j >> 4);
    const int by = p & 15, bz = p >> 4;

    const int lda = 2 * DIM;
    const bf16* Ab = A  + (size_t)bz * SEQ * lda + (size_t)by * 128 * lda;
    const bf16* Bb = Bm + (size_t)bz * SEQ * lda + (size_t)bx * 128 * lda;
    bf16* Cb = C + (size_t)bz * SEQ * SEQ;
    gemm_core64(Ab, Bb, DIM, lda, lda, As, Bs, acc);

    const int lane = threadIdx.x & 63;
    const int wave = threadIdx.x >> 6;
    const int wm = (wave >> 1) * 64, wn = (wave & 1) * 64;
    const int rowBase = by * 128 + wm + ((lane >> 4) * 4);
    const int colBase = bx * 128 + wn + (lane & 15);

#pragma unroll
    for (int mi = 0; mi < 4; ++mi)
#pragma unroll
        for (int ni = 0; ni < 4; ++ni)
#pragma unroll
            for (int rr = 0; rr < 4; ++rr) {
                const float e = __expf(acc[mi][ni][rr] * 0.03125f);
                acc[mi][ni][rr] = e;
                Cb[(size_t)(rowBase + mi * 16 + rr) * SEQ + colBase + ni * 16] =
                    to_bf16(e);
            }

    float* ls = lsum + (size_t)bz * SEQ;
#pragma unroll
    for (int mi = 0; mi < 4; ++mi)
#pragma unroll
        for (int rr = 0; rr < 4; ++rr) {
            float s = acc[mi][0][rr] + acc[mi][1][rr] + acc[mi][2][rr] + acc[mi][3][rr];
            s += __shfl_xor(s, 1);
            s += __shfl_xor(s, 2);
            s += __shfl_xor(s, 4);
            s += __shfl_xor(s, 8);
            if ((lane & 15) == 0)
                atomicAdd(ls + rowBase + mi * 16 + rr, s);
        }
}

// ---------------------------------------------------------------------------
// PV GEMM, K-split=2: each block computes a K=1024 partial of
// (P' @ Vt^T)/l at BM=128 and atomicAdds fp32 into out (pre-zeroed).
// grid = (8, 16, 8): 1024 blocks = 4/CU.
// ---------------------------------------------------------------------------
__global__ __launch_bounds__(256, 4) void gemm_pv(
    const bf16* __restrict__ A, const bf16* __restrict__ Bm, float* __restrict__ C,
    const float* __restrict__ lsum)
{
    __shared__ bf16 As[8192];
    __shared__ bf16 Bs[8192];
    f32x4 acc[4][4] = {};

    const int d = blockIdx.x + 8 * (blockIdx.y + 16 * blockIdx.z);
    const int c = d & 7, j = d >> 3;
    const int bx = j & 7;
    const int p = c + 8 * (j >> 3);
    const int by = p & 15;
    const int z  = p >> 4;              // 0..7
    const int bz = z >> 1, half = z & 1;

    const bf16* Ab = A  + (size_t)bz * SEQ * SEQ + (size_t)by * 128 * SEQ + half * 1024;
    const bf16* Bb = Bm + (size_t)bz * DIM * SEQ + (size_t)bx * 128 * SEQ + half * 1024;
    float* Cb = C + (size_t)bz * SEQ * DIM;
    gemm_core64(Ab, Bb, 1024, SEQ, SEQ, As, Bs, acc);

    const int lane = threadIdx.x & 63;
    const int wave = threadIdx.x >> 6;
    const int wm = (wave >> 1) * 64, wn = (wave & 1) * 64;
    const int rowBase = by * 128 + wm + ((lane >> 4) * 4);
    const int colBase = bx * 128 + wn + (lane & 15);
    const float* ls = lsum + (size_t)bz * SEQ;
#pragma unroll
    for (int mi = 0; mi < 4; ++mi)
#pragma unroll
        for (int rr = 0; rr < 4; ++rr) {
            const float inv = __builtin_amdgcn_rcpf(ls[rowBase + mi * 16 + rr]);
#pragma unroll
            for (int ni = 0; ni < 4; ++ni)
                atomicAdd(&Cb[(size_t)(rowBase + mi * 16 + rr) * DIM + colBase + ni * 16],
                          acc[mi][ni][rr] * inv);
        }
}

// ---------------------------------------------------------------------------
// Fused prep: blocks [0,8192) cast x fp32->bf16; blocks [8192,11264) transpose
// + cast weights; block 11264 zeroes lsum. All branches block-uniform.
// ---------------------------------------------------------------------------
__global__ __launch_bounds__(256) void prep(
    const float* __restrict__ x,  const float* __restrict__ wq,
    const float* __restrict__ wk, const float* __restrict__ wv,
    bf16* __restrict__ xb, bf16* __restrict__ Wt, float* __restrict__ lsum)
{
    __shared__ float tile[32][33];
    const int b = blockIdx.x;
    const int tid = threadIdx.x;
    if (b < 8192) {
        const size_t i = ((size_t)b * 256 + tid) * 4;
        const float4 v = *(const float4*)(x + i);
        bf16x4 o = { to_bf16(v.x), to_bf16(v.y), to_bf16(v.z), to_bf16(v.w) };
        *(bf16x4*)(xb + i) = o;
    } else if (b < 8192 + 3072) {
        const int t   = b - 8192;
        const int sel = t >> 10;
        const int n0  = (t & 31) * 32;
        const int k0  = ((t >> 5) & 31) * 32;
        const float* w = (sel == 0) ? wq : (sel == 1) ? wk : wv;
        const int tx = tid & 31, ty = tid >> 5;
#pragma unroll
        for (int j = 0; j < 32; j += 8)
            tile[ty + j][tx] = w[(size_t)(k0 + ty + j) * 1024 + n0 + tx];
        __syncthreads();
        bf16* dst = Wt + (size_t)sel * 1024 * 1024;
#pragma unroll
        for (int j = 0; j < 32; j += 8)
            dst[(size_t)(n0 + ty + j) * 1024 + k0 + tx] = to_bf16(tile[tx][ty + j]);
    } else {
#pragma unroll
        for (int i = 0; i < 32; ++i)
            lsum[i * 256 + tid] = 0.0f;
    }
}

// ---------------------------------------------------------------------------
extern "C" void kernel_launch(void* const* d_in, const int* in_sizes, int n_in,
                              void* d_out, int out_size, void* d_ws, size_t ws_size,
                              hipStream_t stream)
{
    const float* x  = (const float*)d_in[0];
    const float* wq = (const float*)d_in[1];
    const float* wk = (const float*)d_in[2];
    const float* wv = (const float*)d_in[3];
    float* out = (float*)d_out;
    char* ws = (char*)d_ws;

    // workspace layout (bytes)
    bf16*  xb   = (bf16*)(ws);                   // 16 MB [8192,1024]
    bf16*  Wt   = (bf16*)(ws + (16u << 20));     //  6 MB [3072,1024] (WqT|WkT|WvT)
    bf16*  QK   = (bf16*)(ws + (22u << 20));     // 32 MB [8192,2048]
    bf16*  Vt   = (bf16*)(ws + (54u << 20));     // 16 MB [4][1024][2048]
    bf16*  P    = (bf16*)(ws + (70u << 20));     // 32 MB [4,2048,2048]
    float* lsum = (float*)(ws + (102u << 20));   // 32 KB [8192]

    // zero out for K-split atomic accumulation (graph-capture safe)
    hipMemsetAsync(out, 0, (size_t)BATCH * SEQ * DIM * sizeof(float), stream);

    prep<<<dim3(8192 + 3072 + 1), dim3(256), 0, stream>>>(
        x, wq, wk, wv, xb, Wt, lsum);

    // QK + Vt in one dispatch
    proj_gemm<<<dim3(1536), dim3(256), 0, stream>>>(xb, Wt, QK, Vt);

    // P' = exp(Q @ K^T / 32), row sums -> lsum
    gemm_scores<<<dim3(16, 16, 4), dim3(256), 0, stream>>>(QK, QK + DIM, P, lsum);

    // out += (P'_half @ Vt^T) / l, K-split=2
    gemm_pv<<<dim3(8, 16, 8), dim3(256), 0, stream>>>(P, Vt, out, lsum);
}

// Round 8
// 242.388 us; speedup vs baseline: 1.8340x; 1.1531x over previous
//
#include <hip/hip_runtime.h>
#include <cstdint>
#include <cstddef>

typedef __bf16 bf16;
typedef __bf16 bf16x4 __attribute__((ext_vector_type(4)));
typedef __bf16 bf16x8 __attribute__((ext_vector_type(8)));
typedef float  f32x4  __attribute__((ext_vector_type(4)));

#define BATCH 4
#define SEQ   2048
#define DIM   1024
#define LDP   2112   // padded leading dim for P and Vt (4224 B, de-aliases pow-2 channels)

// RNE float -> bf16
__device__ __forceinline__ bf16 to_bf16(float f) {
    unsigned u = __builtin_bit_cast(unsigned, f);
    u += 0x7fffu + ((u >> 16) & 1u);
    unsigned short h = (unsigned short)(u >> 16);
    return __builtin_bit_cast(bf16, h);
}

// async global->LDS, 16B per lane. LDS base must be wave-uniform; HW adds lane*16.
__device__ __forceinline__ void load16_lds(const bf16* g, bf16* l) {
    __builtin_amdgcn_global_load_lds(
        (__attribute__((address_space(1))) void*)(g),
        (__attribute__((address_space(3))) void*)(l),
        16, 0, 0);
}

// ---------------------------------------------------------------------------
// BK=64 core, XOR-swizzled LDS chunk layout (physical chunk = logical ^ (row&7)
// -> 2-way-max bank aliasing, measured 0 conflicts). BM=128, BN=128.
// 4 waves as 2x2, wave-tile 64x64, acc[4][4] (64 VGPR accumulator; launch_bounds
// waves/EU must stay <= 4 — R6 measured: (256,5) forced VGPR 48 -> 419 MB
// scratch spill, 2.8x slowdown).
// ---------------------------------------------------------------------------
__device__ __forceinline__ void gemm_core64(
    const bf16* __restrict__ Abase, const bf16* __restrict__ Bbase,
    int K, int lda, int ldb, bf16* As, bf16* Bs, f32x4 acc[4][4])
{
    const int tid  = threadIdx.x;
    const int lane = tid & 63;
    const int wave = tid >> 6;
    const int wm   = (wave >> 1) * 64;
    const int wn   = (wave & 1) * 64;
    const int r16  = lane & 15;
    const int g    = lane >> 4;
    const int srow0 = wave * 8 + (lane >> 3);
    const int scoff = (((lane & 7) ^ ((lane >> 3) & 7)) * 8);
    const int ldsW  = wave * 512;

    for (int k0 = 0; k0 < K; k0 += 64) {
        __syncthreads();
#pragma unroll
        for (int j = 0; j < 4; ++j) {
            load16_lds(Abase + (size_t)(j * 32 + srow0) * lda + k0 + scoff,
                       As + j * 2048 + ldsW);
            load16_lds(Bbase + (size_t)(j * 32 + srow0) * ldb + k0 + scoff,
                       Bs + j * 2048 + ldsW);
        }
        __syncthreads();

#pragma unroll
        for (int h = 0; h < 2; ++h) {
            bf16x8 af[4], bfr[4];
            const int p = (h * 4 + g) ^ (r16 & 7);
#pragma unroll
            for (int i = 0; i < 4; ++i) {
                af[i]  = *(const bf16x8*)(As + (wm + i * 16 + r16) * 64 + p * 8);
                bfr[i] = *(const bf16x8*)(Bs + (wn + i * 16 + r16) * 64 + p * 8);
            }
#pragma unroll
            for (int mi = 0; mi < 4; ++mi)
#pragma unroll
                for (int ni = 0; ni < 4; ++ni)
                    acc[mi][ni] = __builtin_amdgcn_mfma_f32_16x16x32_bf16(
                        af[mi], bfr[ni], acc[mi][ni], 0, 0, 0);
        }
    }
}

// ---------------------------------------------------------------------------
// Merged projection GEMM: blocks [0,1024) -> Q,K = X @ W{q,k}T^T (separate
// [8192,1024] buffers, 2KB rows); blocks [1024,1536) -> Vt[b] = WvT @ X[b]^T
// ([1024,LDP] per batch).
// ---------------------------------------------------------------------------
__global__ __launch_bounds__(256, 4) void proj_gemm(
    const bf16* __restrict__ xb, const bf16* __restrict__ Wt,
    bf16* __restrict__ Q, bf16* __restrict__ Kb, bf16* __restrict__ Vt)
{
    __shared__ bf16 As[8192];
    __shared__ bf16 Bs[8192];
    f32x4 acc[4][4] = {};

    const int r = blockIdx.x;
    const bf16 *Ab, *Bb;
    bf16* Cb;
    int bx, ldc;
    if (r < 1024) {                       // Q/K part
        const int c = r & 7, j = r >> 3;
        bx  = j & 15;
        const int byl = c + 8 * (j >> 4);
        Ab = xb + (size_t)byl * 128 * DIM;
        Bb = Wt + (size_t)bx * 128 * DIM;
        bf16* dst = (bx < 8) ? Q : Kb;
        Cb = dst + (size_t)byl * 128 * DIM + (size_t)(bx & 7) * 128;
        ldc = DIM;
    } else {                              // Vt part
        const int u = r - 1024;
        const int c = u & 7, j = u >> 3;
        bx = j & 15;
        const int p = c + 8 * (j >> 4);
        const int byl = p & 7;
        const int bz = p >> 3;
        Ab = Wt + (size_t)2 * DIM * DIM + (size_t)byl * 128 * DIM;
        Bb = xb + (size_t)bz * SEQ * DIM + (size_t)bx * 128 * DIM;
        Cb = Vt + (size_t)bz * DIM * LDP + (size_t)byl * 128 * LDP + (size_t)bx * 128;
        ldc = LDP;
    }
    gemm_core64(Ab, Bb, DIM, DIM, DIM, As, Bs, acc);

    const int lane = threadIdx.x & 63;
    const int wave = threadIdx.x >> 6;
    const int wm = (wave >> 1) * 64, wn = (wave & 1) * 64;
    const int rowO = wm + ((lane >> 4) * 4);
    const int colO = wn + (lane & 15);
#pragma unroll
    for (int mi = 0; mi < 4; ++mi)
#pragma unroll
        for (int ni = 0; ni < 4; ++ni)
#pragma unroll
            for (int rr = 0; rr < 4; ++rr)
                Cb[(size_t)(rowO + mi * 16 + rr) * ldc + colO + ni * 16] =
                    to_bf16(acc[mi][ni][rr]);
}

// ---------------------------------------------------------------------------
// scores GEMM: P' = exp((Q @ K^T)/32) (bf16, ldc=LDP), fp32 row sums via
// atomics. grid = (16, 16, 4). A/B rows are 2KB (separate Q,K buffers).
// ---------------------------------------------------------------------------
__global__ __launch_bounds__(256, 4) void gemm_scores(
    const bf16* __restrict__ Q, const bf16* __restrict__ Kb, bf16* __restrict__ P,
    float* __restrict__ lsum)
{
    __shared__ bf16 As[8192];
    __shared__ bf16 Bs[8192];
    f32x4 acc[4][4] = {};

    const int d = blockIdx.x + 16 * (blockIdx.y + 16 * blockIdx.z);
    const int c = d & 7, j = d >> 3;
    const int bx = j & 15;
    const int p = c + 8 * (j >> 4);
    const int by = p & 15, bz = p >> 4;

    const bf16* Ab = Q  + (size_t)bz * SEQ * DIM + (size_t)by * 128 * DIM;
    const bf16* Bb = Kb + (size_t)bz * SEQ * DIM + (size_t)bx * 128 * DIM;
    bf16* Cb = P + (size_t)bz * SEQ * LDP;
    gemm_core64(Ab, Bb, DIM, DIM, DIM, As, Bs, acc);

    const int lane = threadIdx.x & 63;
    const int wave = threadIdx.x >> 6;
    const int wm = (wave >> 1) * 64, wn = (wave & 1) * 64;
    const int rowBase = by * 128 + wm + ((lane >> 4) * 4);
    const int colBase = bx * 128 + wn + (lane & 15);

#pragma unroll
    for (int mi = 0; mi < 4; ++mi)
#pragma unroll
        for (int ni = 0; ni < 4; ++ni)
#pragma unroll
            for (int rr = 0; rr < 4; ++rr) {
                const float e = __expf(acc[mi][ni][rr] * 0.03125f);
                acc[mi][ni][rr] = e;
                Cb[(size_t)(rowBase + mi * 16 + rr) * LDP + colBase + ni * 16] =
                    to_bf16(e);
            }

    float* ls = lsum + (size_t)bz * SEQ;
#pragma unroll
    for (int mi = 0; mi < 4; ++mi)
#pragma unroll
        for (int rr = 0; rr < 4; ++rr) {
            float s = acc[mi][0][rr] + acc[mi][1][rr] + acc[mi][2][rr] + acc[mi][3][rr];
            s += __shfl_xor(s, 1);
            s += __shfl_xor(s, 2);
            s += __shfl_xor(s, 4);
            s += __shfl_xor(s, 8);
            if ((lane & 15) == 0)
                atomicAdd(ls + rowBase + mi * 16 + rr, s);
        }
}

// ---------------------------------------------------------------------------
// PV GEMM: out = (P' @ Vt^T) / l, fp32, plain stores. grid = (8, 16, 4).
// A=P (lda LDP), B=Vt (ldb LDP), K=2048.
// ---------------------------------------------------------------------------
__global__ __launch_bounds__(256, 4) void gemm_pv(
    const bf16* __restrict__ P, const bf16* __restrict__ Vt, float* __restrict__ C,
    const float* __restrict__ lsum)
{
    __shared__ bf16 As[8192];
    __shared__ bf16 Bs[8192];
    f32x4 acc[4][4] = {};

    const int d = blockIdx.x + 8 * (blockIdx.y + 16 * blockIdx.z);
    const int c = d & 7, j = d >> 3;
    const int bx = j & 7;
    const int p = c + 8 * (j >> 3);
    const int by = p & 15, bz = p >> 4;

    const bf16* Ab = P  + (size_t)bz * SEQ * LDP + (size_t)by * 128 * LDP;
    const bf16* Bb = Vt + (size_t)bz * DIM * LDP + (size_t)bx * 128 * LDP;
    float* Cb = C + (size_t)bz * SEQ * DIM;
    gemm_core64(Ab, Bb, SEQ, LDP, LDP, As, Bs, acc);

    const int lane = threadIdx.x & 63;
    const int wave = threadIdx.x >> 6;
    const int wm = (wave >> 1) * 64, wn = (wave & 1) * 64;
    const int rowBase = by * 128 + wm + ((lane >> 4) * 4);
    const int colBase = bx * 128 + wn + (lane & 15);
    const float* ls = lsum + (size_t)bz * SEQ;
#pragma unroll
    for (int mi = 0; mi < 4; ++mi)
#pragma unroll
        for (int rr = 0; rr < 4; ++rr) {
            const float inv = __builtin_amdgcn_rcpf(ls[rowBase + mi * 16 + rr]);
#pragma unroll
            for (int ni = 0; ni < 4; ++ni)
                Cb[(size_t)(rowBase + mi * 16 + rr) * DIM + colBase + ni * 16] =
                    acc[mi][ni][rr] * inv;
        }
}

// ---------------------------------------------------------------------------
// Fused prep: blocks [0,8192) cast x fp32->bf16; blocks [8192,11264) transpose
// + cast weights; block 11264 zeroes lsum. All branches block-uniform.
// ---------------------------------------------------------------------------
__global__ __launch_bounds__(256) void prep(
    const float* __restrict__ x,  const float* __restrict__ wq,
    const float* __restrict__ wk, const float* __restrict__ wv,
    bf16* __restrict__ xb, bf16* __restrict__ Wt, float* __restrict__ lsum)
{
    __shared__ float tile[32][33];
    const int b = blockIdx.x;
    const int tid = threadIdx.x;
    if (b < 8192) {
        const size_t i = ((size_t)b * 256 + tid) * 4;
        const float4 v = *(const float4*)(x + i);
        bf16x4 o = { to_bf16(v.x), to_bf16(v.y), to_bf16(v.z), to_bf16(v.w) };
        *(bf16x4*)(xb + i) = o;
    } else if (b < 8192 + 3072) {
        const int t   = b - 8192;
        const int sel = t >> 10;
        const int n0  = (t & 31) * 32;
        const int k0  = ((t >> 5) & 31) * 32;
        const float* w = (sel == 0) ? wq : (sel == 1) ? wk : wv;
        const int tx = tid & 31, ty = tid >> 5;
#pragma unroll
        for (int j = 0; j < 32; j += 8)
            tile[ty + j][tx] = w[(size_t)(k0 + ty + j) * 1024 + n0 + tx];
        __syncthreads();
        bf16* dst = Wt + (size_t)sel * 1024 * 1024;
#pragma unroll
        for (int j = 0; j < 32; j += 8)
            dst[(size_t)(n0 + ty + j) * 1024 + k0 + tx] = to_bf16(tile[tx][ty + j]);
    } else {
#pragma unroll
        for (int i = 0; i < 32; ++i)
            lsum[i * 256 + tid] = 0.0f;
    }
}

// ---------------------------------------------------------------------------
extern "C" void kernel_launch(void* const* d_in, const int* in_sizes, int n_in,
                              void* d_out, int out_size, void* d_ws, size_t ws_size,
                              hipStream_t stream)
{
    const float* x  = (const float*)d_in[0];
    const float* wq = (const float*)d_in[1];
    const float* wk = (const float*)d_in[2];
    const float* wv = (const float*)d_in[3];
    float* out = (float*)d_out;
    char* ws = (char*)d_ws;

    // workspace layout (bytes)
    bf16*  xb   = (bf16*)(ws);                   // 16 MB [8192,1024]
    bf16*  Wt   = (bf16*)(ws + (16u << 20));     //  6 MB [3072,1024] (WqT|WkT|WvT)
    bf16*  Q    = (bf16*)(ws + (22u << 20));     // 16 MB [8192,1024]
    bf16*  Kb   = (bf16*)(ws + (38u << 20));     // 16 MB [8192,1024]
    bf16*  Vt   = (bf16*)(ws + (54u << 20));     // 17 MB [4][1024][LDP]
    bf16*  P    = (bf16*)(ws + (72u << 20));     // 33 MB [4][2048][LDP]
    float* lsum = (float*)(ws + (108u << 20));   // 32 KB [8192]

    prep<<<dim3(8192 + 3072 + 1), dim3(256), 0, stream>>>(
        x, wq, wk, wv, xb, Wt, lsum);

    // Q, K, Vt in one dispatch
    proj_gemm<<<dim3(1536), dim3(256), 0, stream>>>(xb, Wt, Q, Kb, Vt);

    // P' = exp(Q @ K^T / 32), row sums -> lsum
    gemm_scores<<<dim3(16, 16, 4), dim3(256), 0, stream>>>(Q, Kb, P, lsum);

    // out = (P' @ Vt^T) / l
    gemm_pv<<<dim3(8, 16, 4), dim3(256), 0, stream>>>(P, Vt, out, lsum);
}

// Round 9
// 237.318 us; speedup vs baseline: 1.8732x; 1.0214x over previous
//
#include <hip/hip_runtime.h>
#include <cstdint>
#include <cstddef>

typedef __bf16 bf16;
typedef __bf16 bf16x4 __attribute__((ext_vector_type(4)));
typedef __bf16 bf16x8 __attribute__((ext_vector_type(8)));
typedef float  f32x4  __attribute__((ext_vector_type(4)));
typedef float  f32x16 __attribute__((ext_vector_type(16)));

#define BATCH 4
#define SEQ   2048
#define DIM   1024
#define LDP   2112   // padded leading dim for P and Vt

// RNE float -> bf16
__device__ __forceinline__ bf16 to_bf16(float f) {
    unsigned u = __builtin_bit_cast(unsigned, f);
    u += 0x7fffu + ((u >> 16) & 1u);
    unsigned short h = (unsigned short)(u >> 16);
    return __builtin_bit_cast(bf16, h);
}

// async global->LDS, 16B per lane. LDS base must be wave-uniform; HW adds lane*16.
__device__ __forceinline__ void load16_lds(const bf16* g, bf16* l) {
    __builtin_amdgcn_global_load_lds(
        (__attribute__((address_space(1))) void*)(g),
        (__attribute__((address_space(3))) void*)(l),
        16, 0, 0);
}

// ---------------------------------------------------------------------------
// Shared staging helper: BK=64, 128x64 A-tile + 128x64 B-tile, XOR-swizzled
// chunk layout (physical 16B-chunk p = logical c ^ (row&7)).
// ---------------------------------------------------------------------------
__device__ __forceinline__ void stage_tiles(
    const bf16* __restrict__ Abase, const bf16* __restrict__ Bbase,
    int k0, int lda, int ldb, bf16* As, bf16* Bs)
{
    const int tid   = threadIdx.x;
    const int wave  = tid >> 6;
    const int lane  = tid & 63;
    const int srow0 = wave * 8 + (lane >> 3);
    const int scoff = (((lane & 7) ^ ((lane >> 3) & 7)) * 8);
    const int ldsW  = wave * 512;
#pragma unroll
    for (int j = 0; j < 4; ++j) {
        load16_lds(Abase + (size_t)(j * 32 + srow0) * lda + k0 + scoff,
                   As + j * 2048 + ldsW);
        load16_lds(Bbase + (size_t)(j * 32 + srow0) * ldb + k0 + scoff,
                   Bs + j * 2048 + ldsW);
    }
}

// ---------------------------------------------------------------------------
// 16x16x32 core (scores): wave 64x64 = 4x4 tiles, acc[4][4] f32x4.
// launch_bounds waves/EU must stay <= 4 (R6: (256,5) -> VGPR 48, spill, 2.8x).
// ---------------------------------------------------------------------------
__device__ __forceinline__ void gemm_core64_16(
    const bf16* __restrict__ Abase, const bf16* __restrict__ Bbase,
    int K, int lda, int ldb, bf16* As, bf16* Bs, f32x4 acc[4][4])
{
    const int tid  = threadIdx.x;
    const int lane = tid & 63;
    const int wave = tid >> 6;
    const int wm   = (wave >> 1) * 64;
    const int wn   = (wave & 1) * 64;
    const int r16  = lane & 15;
    const int g    = lane >> 4;

    for (int k0 = 0; k0 < K; k0 += 64) {
        __syncthreads();
        stage_tiles(Abase, Bbase, k0, lda, ldb, As, Bs);
        __syncthreads();
#pragma unroll
        for (int h = 0; h < 2; ++h) {
            bf16x8 af[4], bfr[4];
            const int p = (h * 4 + g) ^ (r16 & 7);
#pragma unroll
            for (int i = 0; i < 4; ++i) {
                af[i]  = *(const bf16x8*)(As + (wm + i * 16 + r16) * 64 + p * 8);
                bfr[i] = *(const bf16x8*)(Bs + (wn + i * 16 + r16) * 64 + p * 8);
            }
#pragma unroll
            for (int mi = 0; mi < 4; ++mi)
#pragma unroll
                for (int ni = 0; ni < 4; ++ni)
                    acc[mi][ni] = __builtin_amdgcn_mfma_f32_16x16x32_bf16(
                        af[mi], bfr[ni], acc[mi][ni], 0, 0, 0);
        }
    }
}

// ---------------------------------------------------------------------------
// 32x32x16 core (proj, pv): wave 64x64 = 2x2 tiles of 32x32, acc[2][2] f32x16.
// m119: 32x32x16_bf16 = 2495 TF ubench vs 2075 for 16x16x32; half the MFMA
// issues, half the live fragment VGPRs. A/B frag: row=lane&31, k-half=lane>>5,
// 8 contiguous k per lane -> same ds_read_b128 + XOR swizzle.
// ---------------------------------------------------------------------------
__device__ __forceinline__ void gemm_core64_32(
    const bf16* __restrict__ Abase, const bf16* __restrict__ Bbase,
    int K, int lda, int ldb, bf16* As, bf16* Bs, f32x16 acc[2][2])
{
    const int tid  = threadIdx.x;
    const int lane = tid & 63;
    const int wave = tid >> 6;
    const int wm   = (wave >> 1) * 64;
    const int wn   = (wave & 1) * 64;
    const int r32  = lane & 31;
    const int hi   = lane >> 5;

    for (int k0 = 0; k0 < K; k0 += 64) {
        __syncthreads();
        stage_tiles(Abase, Bbase, k0, lda, ldb, As, Bs);
        __syncthreads();
#pragma unroll
        for (int t = 0; t < 4; ++t) {                 // K-phase of 16
            bf16x8 af[2], bfr[2];
            const int p = (2 * t + hi) ^ (r32 & 7);
#pragma unroll
            for (int i = 0; i < 2; ++i) {
                af[i]  = *(const bf16x8*)(As + (wm + i * 32 + r32) * 64 + p * 8);
                bfr[i] = *(const bf16x8*)(Bs + (wn + i * 32 + r32) * 64 + p * 8);
            }
#pragma unroll
            for (int mi = 0; mi < 2; ++mi)
#pragma unroll
                for (int ni = 0; ni < 2; ++ni)
                    acc[mi][ni] = __builtin_amdgcn_mfma_f32_32x32x16_bf16(
                        af[mi], bfr[ni], acc[mi][ni], 0, 0, 0);
        }
    }
}

// row within a 32x32 C tile for accumulator register `reg` (verified mapping)
__device__ __forceinline__ int c32_row(int reg, int hi) {
    return (reg & 3) + 8 * (reg >> 2) + 4 * hi;
}

// ---------------------------------------------------------------------------
// Merged projection GEMM (32x32 core): blocks [0,1024) -> Q,K = X @ W{q,k}T^T;
// blocks [1024,1536) -> Vt[b] = WvT @ X[b]^T ([1024,LDP] per batch).
// ---------------------------------------------------------------------------
__global__ __launch_bounds__(256, 4) void proj_gemm(
    const bf16* __restrict__ xb, const bf16* __restrict__ Wt,
    bf16* __restrict__ Q, bf16* __restrict__ Kb, bf16* __restrict__ Vt)
{
    __shared__ bf16 As[8192];
    __shared__ bf16 Bs[8192];
    f32x16 acc[2][2] = {};

    const int r = blockIdx.x;
    const bf16 *Ab, *Bb;
    bf16* Cb;
    int ldc;
    if (r < 1024) {                       // Q/K part
        const int c = r & 7, j = r >> 3;
        const int bx  = j & 15;
        const int byl = c + 8 * (j >> 4);
        Ab = xb + (size_t)byl * 128 * DIM;
        Bb = Wt + (size_t)bx * 128 * DIM;
        bf16* dst = (bx < 8) ? Q : Kb;
        Cb = dst + (size_t)byl * 128 * DIM + (size_t)(bx & 7) * 128;
        ldc = DIM;
    } else {                              // Vt part
        const int u = r - 1024;
        const int c = u & 7, j = u >> 3;
        const int bx = j & 15;
        const int p = c + 8 * (j >> 4);
        const int byl = p & 7;
        const int bz = p >> 3;
        Ab = Wt + (size_t)2 * DIM * DIM + (size_t)byl * 128 * DIM;
        Bb = xb + (size_t)bz * SEQ * DIM + (size_t)bx * 128 * DIM;
        Cb = Vt + (size_t)bz * DIM * LDP + (size_t)byl * 128 * LDP + (size_t)bx * 128;
        ldc = LDP;
    }
    gemm_core64_32(Ab, Bb, DIM, DIM, DIM, As, Bs, acc);

    const int lane = threadIdx.x & 63;
    const int wave = threadIdx.x >> 6;
    const int hi = lane >> 5, r32 = lane & 31;
    const int wm = (wave >> 1) * 64, wn = (wave & 1) * 64;
#pragma unroll
    for (int mi = 0; mi < 2; ++mi)
#pragma unroll
        for (int ni = 0; ni < 2; ++ni)
#pragma unroll
            for (int reg = 0; reg < 16; ++reg) {
                const int row = wm + mi * 32 + c32_row(reg, hi);
                const int col = wn + ni * 32 + r32;
                Cb[(size_t)row * ldc + col] = to_bf16(acc[mi][ni][reg]);
            }
}

// ---------------------------------------------------------------------------
// scores GEMM (16x16 core, unchanged): P' = exp((Q @ K^T)/32) (bf16, ldc=LDP),
// fp32 row sums via atomics. grid = (16, 16, 4).
// ---------------------------------------------------------------------------
__global__ __launch_bounds__(256, 4) void gemm_scores(
    const bf16* __restrict__ Q, const bf16* __restrict__ Kb, bf16* __restrict__ P,
    float* __restrict__ lsum)
{
    __shared__ bf16 As[8192];
    __shared__ bf16 Bs[8192];
    f32x4 acc[4][4] = {};

    const int d = blockIdx.x + 16 * (blockIdx.y + 16 * blockIdx.z);
    const int c = d & 7, j = d >> 3;
    const int bx = j & 15;
    const int p = c + 8 * (j >> 4);
    const int by = p & 15, bz = p >> 4;

    const bf16* Ab = Q  + (size_t)bz * SEQ * DIM + (size_t)by * 128 * DIM;
    const bf16* Bb = Kb + (size_t)bz * SEQ * DIM + (size_t)bx * 128 * DIM;
    bf16* Cb = P + (size_t)bz * SEQ * LDP;
    gemm_core64_16(Ab, Bb, DIM, DIM, DIM, As, Bs, acc);

    const int lane = threadIdx.x & 63;
    const int wave = threadIdx.x >> 6;
    const int wm = (wave >> 1) * 64, wn = (wave & 1) * 64;
    const int rowBase = by * 128 + wm + ((lane >> 4) * 4);
    const int colBase = bx * 128 + wn + (lane & 15);

#pragma unroll
    for (int mi = 0; mi < 4; ++mi)
#pragma unroll
        for (int ni = 0; ni < 4; ++ni)
#pragma unroll
            for (int rr = 0; rr < 4; ++rr) {
                const float e = __expf(acc[mi][ni][rr] * 0.03125f);
                acc[mi][ni][rr] = e;
                Cb[(size_t)(rowBase + mi * 16 + rr) * LDP + colBase + ni * 16] =
                    to_bf16(e);
            }

    float* ls = lsum + (size_t)bz * SEQ;
#pragma unroll
    for (int mi = 0; mi < 4; ++mi)
#pragma unroll
        for (int rr = 0; rr < 4; ++rr) {
            float s = acc[mi][0][rr] + acc[mi][1][rr] + acc[mi][2][rr] + acc[mi][3][rr];
            s += __shfl_xor(s, 1);
            s += __shfl_xor(s, 2);
            s += __shfl_xor(s, 4);
            s += __shfl_xor(s, 8);
            if ((lane & 15) == 0)
                atomicAdd(ls + rowBase + mi * 16 + rr, s);
        }
}

// ---------------------------------------------------------------------------
// PV GEMM (32x32 core): out = (P' @ Vt^T) / l, fp32. grid = (8, 16, 4).
// ---------------------------------------------------------------------------
__global__ __launch_bounds__(256, 4) void gemm_pv(
    const bf16* __restrict__ P, const bf16* __restrict__ Vt, float* __restrict__ C,
    const float* __restrict__ lsum)
{
    __shared__ bf16 As[8192];
    __shared__ bf16 Bs[8192];
    f32x16 acc[2][2] = {};

    const int d = blockIdx.x + 8 * (blockIdx.y + 16 * blockIdx.z);
    const int c = d & 7, j = d >> 3;
    const int bx = j & 7;
    const int p = c + 8 * (j >> 3);
    const int by = p & 15, bz = p >> 4;

    const bf16* Ab = P  + (size_t)bz * SEQ * LDP + (size_t)by * 128 * LDP;
    const bf16* Bb = Vt + (size_t)bz * DIM * LDP + (size_t)bx * 128 * LDP;
    float* Cb = C + (size_t)bz * SEQ * DIM;
    gemm_core64_32(Ab, Bb, SEQ, LDP, LDP, As, Bs, acc);

    const int lane = threadIdx.x & 63;
    const int wave = threadIdx.x >> 6;
    const int hi = lane >> 5, r32 = lane & 31;
    const int wm = (wave >> 1) * 64, wn = (wave & 1) * 64;
    const int rowBase = by * 128 + wm;
    const int colBase = bx * 128 + wn + r32;
    const float* ls = lsum + (size_t)bz * SEQ;
#pragma unroll
    for (int mi = 0; mi < 2; ++mi)
#pragma unroll
        for (int reg = 0; reg < 16; ++reg) {
            const int row = rowBase + mi * 32 + c32_row(reg, hi);
            const float inv = __builtin_amdgcn_rcpf(ls[row]);
#pragma unroll
            for (int ni = 0; ni < 2; ++ni)
                Cb[(size_t)row * DIM + colBase + ni * 32] = acc[mi][ni][reg] * inv;
        }
}

// ---------------------------------------------------------------------------
// Fused prep: blocks [0,8192) cast x fp32->bf16; blocks [8192,11264) transpose
// + cast weights; block 11264 zeroes lsum. All branches block-uniform.
// ---------------------------------------------------------------------------
__global__ __launch_bounds__(256) void prep(
    const float* __restrict__ x,  const float* __restrict__ wq,
    const float* __restrict__ wk, const float* __restrict__ wv,
    bf16* __restrict__ xb, bf16* __restrict__ Wt, float* __restrict__ lsum)
{
    __shared__ float tile[32][33];
    const int b = blockIdx.x;
    const int tid = threadIdx.x;
    if (b < 8192) {
        const size_t i = ((size_t)b * 256 + tid) * 4;
        const float4 v = *(const float4*)(x + i);
        bf16x4 o = { to_bf16(v.x), to_bf16(v.y), to_bf16(v.z), to_bf16(v.w) };
        *(bf16x4*)(xb + i) = o;
    } else if (b < 8192 + 3072) {
        const int t   = b - 8192;
        const int sel = t >> 10;
        const int n0  = (t & 31) * 32;
        const int k0  = ((t >> 5) & 31) * 32;
        const float* w = (sel == 0) ? wq : (sel == 1) ? wk : wv;
        const int tx = tid & 31, ty = tid >> 5;
#pragma unroll
        for (int j = 0; j < 32; j += 8)
            tile[ty + j][tx] = w[(size_t)(k0 + ty + j) * 1024 + n0 + tx];
        __syncthreads();
        bf16* dst = Wt + (size_t)sel * 1024 * 1024;
#pragma unroll
        for (int j = 0; j < 32; j += 8)
            dst[(size_t)(n0 + ty + j) * 1024 + k0 + tx] = to_bf16(tile[tx][ty + j]);
    } else {
#pragma unroll
        for (int i = 0; i < 32; ++i)
            lsum[i * 256 + tid] = 0.0f;
    }
}

// ---------------------------------------------------------------------------
extern "C" void kernel_launch(void* const* d_in, const int* in_sizes, int n_in,
                              void* d_out, int out_size, void* d_ws, size_t ws_size,
                              hipStream_t stream)
{
    const float* x  = (const float*)d_in[0];
    const float* wq = (const float*)d_in[1];
    const float* wk = (const float*)d_in[2];
    const float* wv = (const float*)d_in[3];
    float* out = (float*)d_out;
    char* ws = (char*)d_ws;

    // workspace layout (bytes)
    bf16*  xb   = (bf16*)(ws);                   // 16 MB [8192,1024]
    bf16*  Wt   = (bf16*)(ws + (16u << 20));     //  6 MB [3072,1024] (WqT|WkT|WvT)
    bf16*  Q    = (bf16*)(ws + (22u << 20));     // 16 MB [8192,1024]
    bf16*  Kb   = (bf16*)(ws + (38u << 20));     // 16 MB [8192,1024]
    bf16*  Vt   = (bf16*)(ws + (54u << 20));     // 17 MB [4][1024][LDP]
    bf16*  P    = (bf16*)(ws + (72u << 20));     // 33 MB [4][2048][LDP]
    float* lsum = (float*)(ws + (108u << 20));   // 32 KB [8192]

    prep<<<dim3(8192 + 3072 + 1), dim3(256), 0, stream>>>(
        x, wq, wk, wv, xb, Wt, lsum);

    // Q, K, Vt in one dispatch
    proj_gemm<<<dim3(1536), dim3(256), 0, stream>>>(xb, Wt, Q, Kb, Vt);

    // P' = exp(Q @ K^T / 32), row sums -> lsum
    gemm_scores<<<dim3(16, 16, 4), dim3(256), 0, stream>>>(Q, Kb, P, lsum);

    // out = (P' @ Vt^T) / l
    gemm_pv<<<dim3(8, 16, 4), dim3(256), 0, stream>>>(P, Vt, out, lsum);
}